// Round 7
// baseline (250.779 us; speedup 1.0000x reference)
//
#include <hip/hip_runtime.h>

namespace {
constexpr int kInCh  = 64;
constexpr int kOutCh = 64;
constexpr int kK     = 3;
constexpr int kFanIn = 8;
constexpr int kH     = 1024;
constexpr int kTile  = 128;          // h-positions per tile
constexpr int kRow   = kTile + 8;    // LDS row: 4-float halo each side, float4-aligned
constexpr int kBlk   = 512;          // 8 waves
constexpr int kTilesPerBlk = 4;      // persistent: 4096 tiles / 1024 blocks
constexpr int kHTiles = kH / kTile;  // 8
}

struct Tap { int off; float w; };

// input fake-quant: clip(round(v*16), -128, 127) * 0.0625
// *16 exact (pow2); rintf = round-half-even = np.round. STE forward == q exactly.
__device__ __forceinline__ float quant_in(float v) {
    float q = rintf(v * 16.0f);
    q = fmaxf(q, -128.0f);
    q = fminf(q, 127.0f);
    return q * 0.0625f;
}

// output fake-quant in fp32 (ref conv+quant is fp32; *8 and *0.125 exact pow2)
__device__ __forceinline__ float quant_out(float v) {
    float q = rintf(v * 8.0f);
    q = fmaxf(q, -128.0f);
    q = fminf(q, 127.0f);
    return q * 0.125f;
}

// VERIFIED (round 4, absmax=0.0): reference == single fp32 FMA chain per output in
// (k-major, ci-minor) tap order — Eigen im2col contraction order. DO NOT change
// tap ordering or accumulation structure.
__global__ void prep_taps(const float* __restrict__ weight,
                          const float* __restrict__ mask,
                          Tap* __restrict__ taps) {
    __shared__ unsigned long long bal[3];
    const int o    = blockIdx.x;
    const int j    = threadIdx.x;        // key: k*64 + ci  (wave index == k)
    const int k    = j >> 6;
    const int ci   = j & 63;
    const int idx  = (o * kInCh + ci) * kK + k;   // OIH storage

    const float m = mask[idx];
    const unsigned long long b = __ballot(m != 0.0f);
    if (ci == 0) bal[k] = b;
    __syncthreads();

    const unsigned long long lower = b & ((1ull << ci) - 1ull);
    int rank = __popcll(lower);
    #pragma unroll
    for (int w = 0; w < kK; ++w) if (w < k) rank += __popcll(bal[w]);

    if (m != 0.0f && rank < kFanIn) {
        taps[o * kFanIn + rank].off = ci * kRow + k + 3;
        taps[o * kFanIn + rank].w   = weight[idx] * m;
    }
    int total = __popcll(bal[0]) + __popcll(bal[1]) + __popcll(bal[2]);
    if (j >= total && j < kFanIn) {     // zero-pad (ws poisoned 0xAA)
        taps[o * kFanIn + j].off = 3;
        taps[o * kFanIn + j].w   = 0.0f;
    }
}

// Persistent blocks, register-prefetch pipeline (m97-style 2-barrier loop).
// Round 6 evidence: occupancy 32->60% left dur flat at ~81us, VALUBusy 23%,
// HBM 35% -> single-barrier phase locking (stage and compute alternate,
// pipes never overlap). Here: loads for tile t+1 issue before compute of
// tile t, so HBM-read overlaps LDS/VALU compute.
__global__ __launch_bounds__(kBlk, 8) void sparse_conv(
        const float* __restrict__ x,
        const Tap*   __restrict__ taps,
        float*       __restrict__ out) {
    __shared__ float sm[kInCh * kRow];   // 34.8 KiB -> 4 blocks/CU, 32 waves/CU

    const int t = threadIdx.x;
    const int tau0 = blockIdx.x * kTilesPerBlk;   // 4 consecutive tiles: same/adjacent n

    float4 r0, r1, r2, r3, rh;   // prefetch registers: 4 main + 1 halo

    auto load_regs = [&](int tau) {
        const int n  = tau >> 3;              // kHTiles == 8
        const int h0 = (tau & 7) * kTile;
        const float* __restrict__ xn = x + (size_t)n * kInCh * kH;
        // 64 rows x 32 float4 = 2048 float4 over 512 threads -> 4 each, coalesced
        {
            int f = t;              r0 = reinterpret_cast<const float4*>(xn + (f >> 5) * kH + h0)[f & 31];
        }
        {
            int f = kBlk + t;       r1 = reinterpret_cast<const float4*>(xn + (f >> 5) * kH + h0)[f & 31];
        }
        {
            int f = 2 * kBlk + t;   r2 = reinterpret_cast<const float4*>(xn + (f >> 5) * kH + h0)[f & 31];
        }
        {
            int f = 3 * kBlk + t;   r3 = reinterpret_cast<const float4*>(xn + (f >> 5) * kH + h0)[f & 31];
        }
        rh = make_float4(0.f, 0.f, 0.f, 0.f);
        if (t < 64) {                               // left halo (only h0-1 read)
            if (h0 > 0) rh = *reinterpret_cast<const float4*>(xn + t * kH + h0 - 4);
        } else if (t < 128) {                       // right halo (only h0+kTile read)
            if (h0 + kTile < kH) rh = *reinterpret_cast<const float4*>(xn + (t - 64) * kH + h0 + kTile);
        }
    };

    auto store_lds = [&](void) {
        auto q4 = [](float4 v) {
            v.x = quant_in(v.x); v.y = quant_in(v.y);
            v.z = quant_in(v.z); v.w = quant_in(v.w);
            return v;
        };
        {
            int f = t;            reinterpret_cast<float4*>(&sm[(f >> 5) * kRow + 4])[f & 31] = q4(r0);
        }
        {
            int f = kBlk + t;     reinterpret_cast<float4*>(&sm[(f >> 5) * kRow + 4])[f & 31] = q4(r1);
        }
        {
            int f = 2 * kBlk + t; reinterpret_cast<float4*>(&sm[(f >> 5) * kRow + 4])[f & 31] = q4(r2);
        }
        {
            int f = 3 * kBlk + t; reinterpret_cast<float4*>(&sm[(f >> 5) * kRow + 4])[f & 31] = q4(r3);
        }
        if (t < 64) {
            *reinterpret_cast<float4*>(&sm[t * kRow]) = q4(rh);
        } else if (t < 128) {
            *reinterpret_cast<float4*>(&sm[(t - 64) * kRow + 4 + kTile]) = q4(rh);
        }
    };

    // ---- prologue: stage tile 0 ----
    load_regs(tau0);
    store_lds();
    __syncthreads();

    const int g = __builtin_amdgcn_readfirstlane(t >> 6);   // wave-uniform o-group (0..7)
    const int i = t & 63;

    #pragma unroll
    for (int it = 0; it < kTilesPerBlk; ++it) {
        const int tau = tau0 + it;
        const int n   = tau >> 3;
        const int h0  = (tau & 7) * kTile;

        if (it + 1 < kTilesPerBlk) load_regs(tau + 1);   // issue early: overlaps compute

        float* __restrict__ outn = out + (size_t)n * kOutCh * kH + h0;
        #pragma unroll 2
        for (int oo = 0; oo < 8; ++oo) {
            int o = g * 8 + oo;
            const Tap* __restrict__ tp = taps + o * kFanIn;
            // Single sequential fp32 FMA chain in (k-major, ci-minor) tap order —
            // bit-matches the reference (verified round 4, absmax = 0.0).
            float acc0 = 0.f, acc1 = 0.f;
            #pragma unroll
            for (int j = 0; j < kFanIn; ++j) {
                int off = tp[j].off; float w = tp[j].w;
                acc0 = fmaf(w, sm[off + i],      acc0);   // ds_read2_b32 pair
                acc1 = fmaf(w, sm[off + i + 64], acc1);
            }
            outn[o * kH + i]      = quant_out(acc0);
            outn[o * kH + i + 64] = quant_out(acc1);
        }

        if (it + 1 < kTilesPerBlk) {
            __syncthreads();      // all waves done reading tile t
            store_lds();          // vmcnt wait on prefetch happens here
            __syncthreads();      // tile t+1 visible to all waves
        }
    }
}

extern "C" void kernel_launch(void* const* d_in, const int* in_sizes, int n_in,
                              void* d_out, int out_size, void* d_ws, size_t ws_size,
                              hipStream_t stream) {
    const float* x      = (const float*)d_in[0];
    const float* weight = (const float*)d_in[1];
    const float* mask   = (const float*)d_in[2];
    float* out = (float*)d_out;
    Tap* taps = (Tap*)d_ws;   // 64*8*8 B = 4 KiB of workspace

    const int nBatch = in_sizes[0] / (kInCh * kH);          // 512
    const int nTiles = nBatch * kHTiles;                    // 4096
    const int nBlocks = nTiles / kTilesPerBlk;              // 1024 = 4 blocks/CU

    prep_taps<<<kOutCh, kInCh * kK, 0, stream>>>(weight, mask, taps);
    sparse_conv<<<nBlocks, kBlk, 0, stream>>>(x, taps, out);
}